// Round 1
// baseline (1354.230 us; speedup 1.0000x reference)
//
#include <hip/hip_runtime.h>

// LearnableSDFGrid: ray-box intersect + fixed-step march + 8-corner voxel gather.
// R=32768 rays, S=128 steps, 256^3 f32 grid, box [-1,1]^3, step 0.02.
// Outputs (concat flat): sdf [R,S,8], positions [R,S,8,3], valid [R,S] (as 0/1 f32).

constexpr int   RAYS = 32768;
constexpr int   STEPS = 128;
constexpr float STEP = 0.02f;
constexpr float VOX = 2.0f / 255.0f;   // (max-min)/(n-1), rounded once in f32 like jnp

typedef float f4 __attribute__((ext_vector_type(4)));

__global__ __launch_bounds__(256) void sdf_march_kernel(
    const float* __restrict__ org,
    const float* __restrict__ dir,
    const float* __restrict__ sdfv,
    float* __restrict__ out_sdf,    // R*S*8
    float* __restrict__ out_pos,    // R*S*8*3
    float* __restrict__ out_valid)  // R*S
{
#pragma clang fp contract(off)
    const int gid = blockIdx.x * 256 + threadIdx.x;
    const int r = gid >> 7;       // ray
    const int s = gid & 127;      // step

    // --- ray-box intersection (faithful to reference, incl. t0 reuse in t1) ---
    const float ox = org[r * 3 + 0], oy = org[r * 3 + 1], oz = org[r * 3 + 2];
    const float dx = dir[r * 3 + 0], dy = dir[r * 3 + 1], dz = dir[r * 3 + 2];

    const float ivx = 1.0f / dx, ivy = 1.0f / dy, ivz = 1.0f / dz;
    const float axv = (-1.0f - ox) * ivx, ayv = (-1.0f - oy) * ivy, azv = (-1.0f - oz) * ivz;
    const float bxv = ( 1.0f - ox) * ivx, byv = ( 1.0f - oy) * ivy, bzv = ( 1.0f - oz) * ivz;
    const float t0 = fmaxf(fmaxf(fminf(axv, bxv), fminf(ayv, byv)), fminf(azv, bzv));
    const float t1 = fminf(fminf(fmaxf(t0, bxv), fmaxf(t0, byv)), fmaxf(t0, bzv));
    const bool hit = (t1 >= t0);

    // --- march: t = t0 + STEP*s (mul then add, separate rounding like numpy) ---
    const float ts = STEP * (float)s;
    const float t  = t0 + ts;
    const bool step_mask = (t < t1) && hit;

    // pts = o + t*d (mul then add; contract off)
    const float mx = t * dx, my = t * dy, mz = t * dz;
    const float px = ox + mx, py = oy + my, pz = oz + mz;

    // idx = trunc((p - minb)/vox) like .astype(int32)
    const float fx = (px + 1.0f) / VOX;
    const float fy = (py + 1.0f) / VOX;
    const float fz = (pz + 1.0f) / VOX;
    const int ix = (int)fx, iy = (int)fy, iz = (int)fz;
    const bool inb = (ix >= 0) & (ix < 255) & (iy >= 0) & (iy < 255) & (iz >= 0) & (iz < 255);
    const bool valid = inb && step_mask;

    const int ixc = min(max(ix, 0), 254);
    const int iyc = min(max(iy, 0), 254);
    const int izc = min(max(iz, 0), 254);

    f4 sv0 = {0.f, 0.f, 0.f, 0.f}, sv1 = {0.f, 0.f, 0.f, 0.f};
    f4 p0 = sv0, p1 = sv0, p2 = sv0, p3 = sv0, p4 = sv0, p5 = sv0;

    if (valid) {
        // 8-corner gather; corner order per OFFS: (0,0,0)(1,0,0)(0,1,0)(1,1,0)(0,0,1)(1,0,1)(0,1,1)(1,1,1)
        const int base = (ixc * 256 + iyc) * 256 + izc;
        const float v000 = sdfv[base];
        const float v100 = sdfv[base + 65536];
        const float v010 = sdfv[base + 256];
        const float v110 = sdfv[base + 65536 + 256];
        const float v001 = sdfv[base + 1];
        const float v101 = sdfv[base + 65536 + 1];
        const float v011 = sdfv[base + 256 + 1];
        const float v111 = sdfv[base + 65536 + 256 + 1];
        sv0 = (f4){v000, v100, v010, v110};
        sv1 = (f4){v001, v101, v011, v111};

        // corner positions: minb + ci*vox (mul then add; contract off)
        const float x0 = -1.0f + (float)ixc * VOX;
        const float x1 = -1.0f + (float)(ixc + 1) * VOX;
        const float y0 = -1.0f + (float)iyc * VOX;
        const float y1 = -1.0f + (float)(iyc + 1) * VOX;
        const float z0 = -1.0f + (float)izc * VOX;
        const float z1 = -1.0f + (float)(izc + 1) * VOX;

        // [8,3] flattened:
        // (x0,y0,z0)(x1,y0,z0)(x0,y1,z0)(x1,y1,z0)(x0,y0,z1)(x1,y0,z1)(x0,y1,z1)(x1,y1,z1)
        p0 = (f4){x0, y0, z0, x1};
        p1 = (f4){y0, z0, x0, y1};
        p2 = (f4){z0, x1, y1, z0};
        p3 = (f4){x0, y0, z1, x1};
        p4 = (f4){y0, z1, x0, y1};
        p5 = (f4){z1, x1, y1, z1};
    }

    // --- streaming (non-temporal) stores: don't thrash L3, keep sdf grid resident ---
    f4* sp = (f4*)(out_sdf + (size_t)gid * 8);
    __builtin_nontemporal_store(sv0, sp + 0);
    __builtin_nontemporal_store(sv1, sp + 1);

    f4* pp = (f4*)(out_pos + (size_t)gid * 24);
    __builtin_nontemporal_store(p0, pp + 0);
    __builtin_nontemporal_store(p1, pp + 1);
    __builtin_nontemporal_store(p2, pp + 2);
    __builtin_nontemporal_store(p3, pp + 3);
    __builtin_nontemporal_store(p4, pp + 4);
    __builtin_nontemporal_store(p5, pp + 5);

    __builtin_nontemporal_store(valid ? 1.0f : 0.0f, out_valid + gid);
}

extern "C" void kernel_launch(void* const* d_in, const int* in_sizes, int n_in,
                              void* d_out, int out_size, void* d_ws, size_t ws_size,
                              hipStream_t stream) {
    const float* origins    = (const float*)d_in[0];
    const float* directions = (const float*)d_in[1];
    const float* sdf_values = (const float*)d_in[2];

    float* out = (float*)d_out;
    float* out_sdf   = out;                                   // 32768*128*8   = 33554432
    float* out_pos   = out + 33554432;                        // 32768*128*8*3 = 100663296
    float* out_valid = out + 33554432 + 100663296;            // 32768*128     = 4194304

    const int total = RAYS * STEPS;                           // 4194304
    dim3 grid(total / 256), block(256);
    sdf_march_kernel<<<grid, block, 0, stream>>>(origins, directions, sdf_values,
                                                 out_sdf, out_pos, out_valid);
}

// Round 3
// 648.850 us; speedup vs baseline: 2.0871x; 2.0871x over previous
//
#include <hip/hip_runtime.h>

// LearnableSDFGrid: ray-box intersect + fixed-step march + 8-corner voxel gather.
// R=32768 rays, S=128 steps, 256^3 f32 grid, box [-1,1]^3, step 0.02.
// Outputs (concat flat): sdf [R,S,8], positions [R,S,8,3], valid [R,S] (as 0/1 f32).
//
// Round 2 (resubmit after broker timeout): plain (cached) stores instead of
// non-temporal. NT 16B/lane stores at 96B lane-stride caused partial-line
// evictions -> 2.7x HBM write amplification (WRITE_SIZE 1.50 GB vs 554 MB
// ideal) and store-queue stalls (VALUBusy 2%).

constexpr int   RAYS = 32768;
constexpr int   STEPS = 128;
constexpr float STEP = 0.02f;
constexpr float VOX = 2.0f / 255.0f;   // (max-min)/(n-1), rounded once in f32 like jnp

typedef float f4 __attribute__((ext_vector_type(4)));

__global__ __launch_bounds__(256) void sdf_march_kernel(
    const float* __restrict__ org,
    const float* __restrict__ dir,
    const float* __restrict__ sdfv,
    float* __restrict__ out_sdf,    // R*S*8
    float* __restrict__ out_pos,    // R*S*8*3
    float* __restrict__ out_valid)  // R*S
{
#pragma clang fp contract(off)
    const int gid = blockIdx.x * 256 + threadIdx.x;
    const int r = gid >> 7;       // ray
    const int s = gid & 127;      // step

    // --- ray-box intersection (faithful to reference, incl. t0 reuse in t1) ---
    const float ox = org[r * 3 + 0], oy = org[r * 3 + 1], oz = org[r * 3 + 2];
    const float dx = dir[r * 3 + 0], dy = dir[r * 3 + 1], dz = dir[r * 3 + 2];

    const float ivx = 1.0f / dx, ivy = 1.0f / dy, ivz = 1.0f / dz;
    const float axv = (-1.0f - ox) * ivx, ayv = (-1.0f - oy) * ivy, azv = (-1.0f - oz) * ivz;
    const float bxv = ( 1.0f - ox) * ivx, byv = ( 1.0f - oy) * ivy, bzv = ( 1.0f - oz) * ivz;
    const float t0 = fmaxf(fmaxf(fminf(axv, bxv), fminf(ayv, byv)), fminf(azv, bzv));
    const float t1 = fminf(fminf(fmaxf(t0, bxv), fmaxf(t0, byv)), fmaxf(t0, bzv));
    const bool hit = (t1 >= t0);

    // --- march: t = t0 + STEP*s (mul then add, separate rounding like numpy) ---
    const float ts = STEP * (float)s;
    const float t  = t0 + ts;
    const bool step_mask = (t < t1) && hit;

    // pts = o + t*d (mul then add; contract off)
    const float mx = t * dx, my = t * dy, mz = t * dz;
    const float px = ox + mx, py = oy + my, pz = oz + mz;

    // idx = trunc((p - minb)/vox) like .astype(int32)
    const float fx = (px + 1.0f) / VOX;
    const float fy = (py + 1.0f) / VOX;
    const float fz = (pz + 1.0f) / VOX;
    const int ix = (int)fx, iy = (int)fy, iz = (int)fz;
    const bool inb = (ix >= 0) & (ix < 255) & (iy >= 0) & (iy < 255) & (iz >= 0) & (iz < 255);
    const bool valid = inb && step_mask;

    const int ixc = min(max(ix, 0), 254);
    const int iyc = min(max(iy, 0), 254);
    const int izc = min(max(iz, 0), 254);

    f4 sv0 = {0.f, 0.f, 0.f, 0.f}, sv1 = {0.f, 0.f, 0.f, 0.f};
    f4 p0 = sv0, p1 = sv0, p2 = sv0, p3 = sv0, p4 = sv0, p5 = sv0;

    if (valid) {
        // 8-corner gather; corner order per OFFS: (0,0,0)(1,0,0)(0,1,0)(1,1,0)(0,0,1)(1,0,1)(0,1,1)(1,1,1)
        const int base = (ixc * 256 + iyc) * 256 + izc;
        const float v000 = sdfv[base];
        const float v100 = sdfv[base + 65536];
        const float v010 = sdfv[base + 256];
        const float v110 = sdfv[base + 65536 + 256];
        const float v001 = sdfv[base + 1];
        const float v101 = sdfv[base + 65536 + 1];
        const float v011 = sdfv[base + 256 + 1];
        const float v111 = sdfv[base + 65536 + 256 + 1];
        sv0 = (f4){v000, v100, v010, v110};
        sv1 = (f4){v001, v101, v011, v111};

        // corner positions: minb + ci*vox (mul then add; contract off)
        const float x0 = -1.0f + (float)ixc * VOX;
        const float x1 = -1.0f + (float)(ixc + 1) * VOX;
        const float y0 = -1.0f + (float)iyc * VOX;
        const float y1 = -1.0f + (float)(iyc + 1) * VOX;
        const float z0 = -1.0f + (float)izc * VOX;
        const float z1 = -1.0f + (float)(izc + 1) * VOX;

        // [8,3] flattened:
        // (x0,y0,z0)(x1,y0,z0)(x0,y1,z0)(x1,y1,z0)(x0,y0,z1)(x1,y0,z1)(x0,y1,z1)(x1,y1,z1)
        p0 = (f4){x0, y0, z0, x1};
        p1 = (f4){y0, z0, x0, y1};
        p2 = (f4){z0, x1, y1, z0};
        p3 = (f4){x0, y0, z1, x1};
        p4 = (f4){y0, z1, x0, y1};
        p5 = (f4){z1, x1, y1, z1};
    }

    // --- plain cached stores: back-to-back stores to each 128B line merge in L2,
    // evictions are full lines (no partial-sector write amplification) ---
    f4* sp = (f4*)(out_sdf + (size_t)gid * 8);
    sp[0] = sv0;
    sp[1] = sv1;

    f4* pp = (f4*)(out_pos + (size_t)gid * 24);
    pp[0] = p0;
    pp[1] = p1;
    pp[2] = p2;
    pp[3] = p3;
    pp[4] = p4;
    pp[5] = p5;

    out_valid[gid] = valid ? 1.0f : 0.0f;
}

extern "C" void kernel_launch(void* const* d_in, const int* in_sizes, int n_in,
                              void* d_out, int out_size, void* d_ws, size_t ws_size,
                              hipStream_t stream) {
    const float* origins    = (const float*)d_in[0];
    const float* directions = (const float*)d_in[1];
    const float* sdf_values = (const float*)d_in[2];

    float* out = (float*)d_out;
    float* out_sdf   = out;                                   // 32768*128*8   = 33554432
    float* out_pos   = out + 33554432;                        // 32768*128*8*3 = 100663296
    float* out_valid = out + 33554432 + 100663296;            // 32768*128     = 4194304

    const int total = RAYS * STEPS;                           // 4194304
    dim3 grid(total / 256), block(256);
    sdf_march_kernel<<<grid, block, 0, stream>>>(origins, directions, sdf_values,
                                                 out_sdf, out_pos, out_valid);
}

// Round 4
// 595.563 us; speedup vs baseline: 2.2739x; 1.0895x over previous
//
#include <hip/hip_runtime.h>

// LearnableSDFGrid: ray-box intersect + fixed-step march + 8-corner voxel gather.
// R=32768 rays, S=128 steps, 256^3 f32 grid, box [-1,1]^3, step 0.02.
// Outputs (concat flat): sdf [R,S,8], positions [R,S,8,3], valid [R,S] (as 0/1 f32).
//
// Round 4: LDS-staged store transpose. Per-thread 96B pos records meant every
// store instruction scattered 64 lanes at 96B stride (~48 line-transactions vs 8
// ideal) -> TA-throttled. Stage pos+sdf in 32KB LDS, barrier, write out as
// lane-contiguous f4 streams. Final stores are full-line coalesced, so NT
// (evict-first) is safe again and keeps the 554MB write stream out of L3,
// leaving the 67MB grid resident for the gathers.

constexpr int   RAYS = 32768;
constexpr int   STEPS = 128;
constexpr float STEP = 0.02f;
constexpr float VOX = 2.0f / 255.0f;   // (max-min)/(n-1), rounded once in f32 like jnp

typedef float f4 __attribute__((ext_vector_type(4)));

__global__ __launch_bounds__(256) void sdf_march_kernel(
    const float* __restrict__ org,
    const float* __restrict__ dir,
    const float* __restrict__ sdfv,
    float* __restrict__ out_sdf,    // R*S*8
    float* __restrict__ out_pos,    // R*S*8*3
    float* __restrict__ out_valid)  // R*S
{
#pragma clang fp contract(off)
    __shared__ f4 lds[2048];            // 1536 pos f4 + 512 sdf f4 = 32 KB

    const int tid = threadIdx.x;
    const int gid = blockIdx.x * 256 + tid;
    const int r = gid >> 7;       // ray
    const int s = gid & 127;      // step

    // --- ray-box intersection (faithful to reference, incl. t0 reuse in t1) ---
    const float ox = org[r * 3 + 0], oy = org[r * 3 + 1], oz = org[r * 3 + 2];
    const float dx = dir[r * 3 + 0], dy = dir[r * 3 + 1], dz = dir[r * 3 + 2];

    const float ivx = 1.0f / dx, ivy = 1.0f / dy, ivz = 1.0f / dz;
    const float axv = (-1.0f - ox) * ivx, ayv = (-1.0f - oy) * ivy, azv = (-1.0f - oz) * ivz;
    const float bxv = ( 1.0f - ox) * ivx, byv = ( 1.0f - oy) * ivy, bzv = ( 1.0f - oz) * ivz;
    const float t0 = fmaxf(fmaxf(fminf(axv, bxv), fminf(ayv, byv)), fminf(azv, bzv));
    const float t1 = fminf(fminf(fmaxf(t0, bxv), fmaxf(t0, byv)), fmaxf(t0, bzv));
    const bool hit = (t1 >= t0);

    // --- march: t = t0 + STEP*s (mul then add, separate rounding like numpy) ---
    const float ts = STEP * (float)s;
    const float t  = t0 + ts;
    const bool step_mask = (t < t1) && hit;

    // pts = o + t*d (mul then add; contract off)
    const float mx = t * dx, my = t * dy, mz = t * dz;
    const float px = ox + mx, py = oy + my, pz = oz + mz;

    // idx = trunc((p - minb)/vox) like .astype(int32)
    const float fx = (px + 1.0f) / VOX;
    const float fy = (py + 1.0f) / VOX;
    const float fz = (pz + 1.0f) / VOX;
    const int ix = (int)fx, iy = (int)fy, iz = (int)fz;
    const bool inb = (ix >= 0) & (ix < 255) & (iy >= 0) & (iy < 255) & (iz >= 0) & (iz < 255);
    const bool valid = inb && step_mask;

    const int ixc = min(max(ix, 0), 254);
    const int iyc = min(max(iy, 0), 254);
    const int izc = min(max(iz, 0), 254);

    f4 sv0 = {0.f, 0.f, 0.f, 0.f}, sv1 = {0.f, 0.f, 0.f, 0.f};
    f4 p0 = sv0, p1 = sv0, p2 = sv0, p3 = sv0, p4 = sv0, p5 = sv0;

    if (valid) {
        // 8-corner gather; corner order per OFFS: (0,0,0)(1,0,0)(0,1,0)(1,1,0)(0,0,1)(1,0,1)(0,1,1)(1,1,1)
        const int base = (ixc * 256 + iyc) * 256 + izc;
        const float v000 = sdfv[base];
        const float v100 = sdfv[base + 65536];
        const float v010 = sdfv[base + 256];
        const float v110 = sdfv[base + 65536 + 256];
        const float v001 = sdfv[base + 1];
        const float v101 = sdfv[base + 65536 + 1];
        const float v011 = sdfv[base + 256 + 1];
        const float v111 = sdfv[base + 65536 + 256 + 1];
        sv0 = (f4){v000, v100, v010, v110};
        sv1 = (f4){v001, v101, v011, v111};

        // corner positions: minb + ci*vox (mul then add; contract off)
        const float x0 = -1.0f + (float)ixc * VOX;
        const float x1 = -1.0f + (float)(ixc + 1) * VOX;
        const float y0 = -1.0f + (float)iyc * VOX;
        const float y1 = -1.0f + (float)(iyc + 1) * VOX;
        const float z0 = -1.0f + (float)izc * VOX;
        const float z1 = -1.0f + (float)(izc + 1) * VOX;

        // record layout [8,3]: (x0,y0,z0)(x1,y0,z0)(x0,y1,z0)(x1,y1,z0)
        //                      (x0,y0,z1)(x1,y0,z1)(x0,y1,z1)(x1,y1,z1)
        p0 = (f4){x0, y0, z0, x1};
        p1 = (f4){y0, z0, x0, y1};
        p2 = (f4){z0, x1, y1, z0};
        p3 = (f4){x0, y0, z1, x1};
        p4 = (f4){y0, z1, x0, y1};
        p5 = (f4){z1, x1, y1, z1};
    }

    // --- stage into LDS (record-major), then write out lane-contiguous ---
    f4* lp = lds;          // 1536 f4: block's pos records, compact
    f4* ls = lds + 1536;   // 512 f4: block's sdf records, compact
    lp[tid * 6 + 0] = p0;
    lp[tid * 6 + 1] = p1;
    lp[tid * 6 + 2] = p2;
    lp[tid * 6 + 3] = p3;
    lp[tid * 6 + 4] = p4;
    lp[tid * 6 + 5] = p5;
    ls[tid * 2 + 0] = sv0;
    ls[tid * 2 + 1] = sv1;

    // valid: 1 dword/lane, already a coalesced full-line stream
    __builtin_nontemporal_store(valid ? 1.0f : 0.0f, out_valid + gid);

    __syncthreads();

    // pos: block's 1536 f4 are globally contiguous at f4-index blockIdx.x*1536
    f4* op = (f4*)out_pos + (size_t)blockIdx.x * 1536;
#pragma unroll
    for (int k = 0; k < 6; ++k) {
        __builtin_nontemporal_store(lp[tid + 256 * k], op + tid + 256 * k);
    }
    // sdf: block's 512 f4 contiguous at f4-index blockIdx.x*512
    f4* os = (f4*)out_sdf + (size_t)blockIdx.x * 512;
#pragma unroll
    for (int k = 0; k < 2; ++k) {
        __builtin_nontemporal_store(ls[tid + 256 * k], os + tid + 256 * k);
    }
}

extern "C" void kernel_launch(void* const* d_in, const int* in_sizes, int n_in,
                              void* d_out, int out_size, void* d_ws, size_t ws_size,
                              hipStream_t stream) {
    const float* origins    = (const float*)d_in[0];
    const float* directions = (const float*)d_in[1];
    const float* sdf_values = (const float*)d_in[2];

    float* out = (float*)d_out;
    float* out_sdf   = out;                                   // 32768*128*8   = 33554432
    float* out_pos   = out + 33554432;                        // 32768*128*8*3 = 100663296
    float* out_valid = out + 33554432 + 100663296;            // 32768*128     = 4194304

    const int total = RAYS * STEPS;                           // 4194304
    dim3 grid(total / 256), block(256);
    sdf_march_kernel<<<grid, block, 0, stream>>>(origins, directions, sdf_values,
                                                 out_sdf, out_pos, out_valid);
}

// Round 5
// 594.704 us; speedup vs baseline: 2.2772x; 1.0014x over previous
//
#include <hip/hip_runtime.h>

// LearnableSDFGrid: ray-box intersect + fixed-step march + 8-corner voxel gather.
// R=32768 rays, S=128 steps, 256^3 f32 grid, box [-1,1]^3, step 0.02.
// Outputs (concat flat): sdf [R,S,8], positions [R,S,8,3], valid [R,S] (as 0/1 f32).
//
// Round 5: merge z-adjacent corner pairs into 8B gather loads. The 8 scattered
// 4B gathers/thread were ~512 TA transactions/wave (~55us across the kernel,
// matching the measured gap over the write-BW floor). Corners (v*0,v*1) are
// contiguous -> 4x dwordx2 halves gather transactions. aligned(4) vector type
// keeps the load legal at odd z (gfx9+ unaligned global access).
// Retained from earlier rounds: LDS-staged store transpose (full-line NT
// stores, no partial-line write amplification), contract(off) numerics.

constexpr int   RAYS = 32768;
constexpr int   STEPS = 128;
constexpr float STEP = 0.02f;
constexpr float VOX = 2.0f / 255.0f;   // (max-min)/(n-1), rounded once in f32 like jnp

typedef float f4 __attribute__((ext_vector_type(4)));
typedef float f2 __attribute__((ext_vector_type(2), aligned(4)));  // 4B-aligned 8B load

__global__ __launch_bounds__(256) void sdf_march_kernel(
    const float* __restrict__ org,
    const float* __restrict__ dir,
    const float* __restrict__ sdfv,
    float* __restrict__ out_sdf,    // R*S*8
    float* __restrict__ out_pos,    // R*S*8*3
    float* __restrict__ out_valid)  // R*S
{
#pragma clang fp contract(off)
    __shared__ f4 lds[2048];            // 1536 pos f4 + 512 sdf f4 = 32 KB

    const int tid = threadIdx.x;
    const int gid = blockIdx.x * 256 + tid;
    const int r = gid >> 7;       // ray
    const int s = gid & 127;      // step

    // --- ray-box intersection (faithful to reference, incl. t0 reuse in t1) ---
    const float ox = org[r * 3 + 0], oy = org[r * 3 + 1], oz = org[r * 3 + 2];
    const float dx = dir[r * 3 + 0], dy = dir[r * 3 + 1], dz = dir[r * 3 + 2];

    const float ivx = 1.0f / dx, ivy = 1.0f / dy, ivz = 1.0f / dz;
    const float axv = (-1.0f - ox) * ivx, ayv = (-1.0f - oy) * ivy, azv = (-1.0f - oz) * ivz;
    const float bxv = ( 1.0f - ox) * ivx, byv = ( 1.0f - oy) * ivy, bzv = ( 1.0f - oz) * ivz;
    const float t0 = fmaxf(fmaxf(fminf(axv, bxv), fminf(ayv, byv)), fminf(azv, bzv));
    const float t1 = fminf(fminf(fmaxf(t0, bxv), fmaxf(t0, byv)), fmaxf(t0, bzv));
    const bool hit = (t1 >= t0);

    // --- march: t = t0 + STEP*s (mul then add, separate rounding like numpy) ---
    const float ts = STEP * (float)s;
    const float t  = t0 + ts;
    const bool step_mask = (t < t1) && hit;

    // pts = o + t*d (mul then add; contract off)
    const float mx = t * dx, my = t * dy, mz = t * dz;
    const float px = ox + mx, py = oy + my, pz = oz + mz;

    // idx = trunc((p - minb)/vox) like .astype(int32)
    const float fx = (px + 1.0f) / VOX;
    const float fy = (py + 1.0f) / VOX;
    const float fz = (pz + 1.0f) / VOX;
    const int ix = (int)fx, iy = (int)fy, iz = (int)fz;
    const bool inb = (ix >= 0) & (ix < 255) & (iy >= 0) & (iy < 255) & (iz >= 0) & (iz < 255);
    const bool valid = inb && step_mask;

    const int ixc = min(max(ix, 0), 254);
    const int iyc = min(max(iy, 0), 254);
    const int izc = min(max(iz, 0), 254);

    f4 sv0 = {0.f, 0.f, 0.f, 0.f}, sv1 = {0.f, 0.f, 0.f, 0.f};
    f4 p0 = sv0, p1 = sv0, p2 = sv0, p3 = sv0, p4 = sv0, p5 = sv0;

    if (valid) {
        // 8-corner gather as 4 z-pair dwordx2 loads.
        // corner order per OFFS: (0,0,0)(1,0,0)(0,1,0)(1,1,0)(0,0,1)(1,0,1)(0,1,1)(1,1,1)
        const int base = (ixc * 256 + iyc) * 256 + izc;
        const f2 vz00 = *(const f2*)(sdfv + base);                  // v000, v001
        const f2 vz10 = *(const f2*)(sdfv + base + 65536);          // v100, v101
        const f2 vz01 = *(const f2*)(sdfv + base + 256);            // v010, v011
        const f2 vz11 = *(const f2*)(sdfv + base + 65536 + 256);    // v110, v111
        sv0 = (f4){vz00.x, vz10.x, vz01.x, vz11.x};
        sv1 = (f4){vz00.y, vz10.y, vz01.y, vz11.y};

        // corner positions: minb + ci*vox (mul then add; contract off)
        const float x0 = -1.0f + (float)ixc * VOX;
        const float x1 = -1.0f + (float)(ixc + 1) * VOX;
        const float y0 = -1.0f + (float)iyc * VOX;
        const float y1 = -1.0f + (float)(iyc + 1) * VOX;
        const float z0 = -1.0f + (float)izc * VOX;
        const float z1 = -1.0f + (float)(izc + 1) * VOX;

        // record layout [8,3]: (x0,y0,z0)(x1,y0,z0)(x0,y1,z0)(x1,y1,z0)
        //                      (x0,y0,z1)(x1,y0,z1)(x0,y1,z1)(x1,y1,z1)
        p0 = (f4){x0, y0, z0, x1};
        p1 = (f4){y0, z0, x0, y1};
        p2 = (f4){z0, x1, y1, z0};
        p3 = (f4){x0, y0, z1, x1};
        p4 = (f4){y0, z1, x0, y1};
        p5 = (f4){z1, x1, y1, z1};
    }

    // --- stage into LDS (record-major), then write out lane-contiguous ---
    f4* lp = lds;          // 1536 f4: block's pos records, compact
    f4* ls = lds + 1536;   // 512 f4: block's sdf records, compact
    lp[tid * 6 + 0] = p0;
    lp[tid * 6 + 1] = p1;
    lp[tid * 6 + 2] = p2;
    lp[tid * 6 + 3] = p3;
    lp[tid * 6 + 4] = p4;
    lp[tid * 6 + 5] = p5;
    ls[tid * 2 + 0] = sv0;
    ls[tid * 2 + 1] = sv1;

    // valid: 1 dword/lane, already a coalesced full-line stream
    __builtin_nontemporal_store(valid ? 1.0f : 0.0f, out_valid + gid);

    __syncthreads();

    // pos: block's 1536 f4 are globally contiguous at f4-index blockIdx.x*1536
    f4* op = (f4*)out_pos + (size_t)blockIdx.x * 1536;
#pragma unroll
    for (int k = 0; k < 6; ++k) {
        __builtin_nontemporal_store(lp[tid + 256 * k], op + tid + 256 * k);
    }
    // sdf: block's 512 f4 contiguous at f4-index blockIdx.x*512
    f4* os = (f4*)out_sdf + (size_t)blockIdx.x * 512;
#pragma unroll
    for (int k = 0; k < 2; ++k) {
        __builtin_nontemporal_store(ls[tid + 256 * k], os + tid + 256 * k);
    }
}

extern "C" void kernel_launch(void* const* d_in, const int* in_sizes, int n_in,
                              void* d_out, int out_size, void* d_ws, size_t ws_size,
                              hipStream_t stream) {
    const float* origins    = (const float*)d_in[0];
    const float* directions = (const float*)d_in[1];
    const float* sdf_values = (const float*)d_in[2];

    float* out = (float*)d_out;
    float* out_sdf   = out;                                   // 32768*128*8   = 33554432
    float* out_pos   = out + 33554432;                        // 32768*128*8*3 = 100663296
    float* out_valid = out + 33554432 + 100663296;            // 32768*128     = 4194304

    const int total = RAYS * STEPS;                           // 4194304
    dim3 grid(total / 256), block(256);
    sdf_march_kernel<<<grid, block, 0, stream>>>(origins, directions, sdf_values,
                                                 out_sdf, out_pos, out_valid);
}